// Round 2
// baseline (20884.167 us; speedup 1.0000x reference)
//
#include <hip/hip_runtime.h>
#include <cmath>

#define NB    256   // batch
#define NT    64    // time points
#define DATA  256
#define AUGD  8
#define DD    264   // DATA + AUG
#define WID   256   // MLP width
#define NSUB  4

struct Params {
  const float *W0, *b0, *W1, *b1, *W2, *b2, *W3, *b3;
};

template <int N4>
__device__ __forceinline__ float dot_chunk(const float* __restrict__ wrow,
                                           const float* __restrict__ fin) {
  const float4* __restrict__ wp = reinterpret_cast<const float4*>(wrow);
  const float4* __restrict__ fp = reinterpret_cast<const float4*>(fin);
  float s = 0.f;
#pragma unroll
  for (int i = 0; i < N4; ++i) {
    float4 w = wp[i];
    float4 f = fp[i];
    s = fmaf(w.x, f.x, s);
    s = fmaf(w.y, f.y, s);
    s = fmaf(w.z, f.z, s);
    s = fmaf(w.w, f.w, s);
  }
  return s;
}

// One dense layer: out[N] = act(Wm[N,K] @ fin[K] + bias[N])
// 512 threads: thread (j = tid&255, q = tid>>8) does half-K partial of row j.
// Rows 256..N-1 (N=264 case) are handled by threads tid<16 as extra tasks.
template <int K, int N, bool DO_TANH>
__device__ __forceinline__ void layer(const float* __restrict__ Wm,
                                      const float* __restrict__ bias,
                                      const float* __restrict__ fin,
                                      float* __restrict__ fout,
                                      float (*__restrict__ ps)[DD],
                                      int j, int q, int tid) {
  constexpr int KH = K / 2;          // 132 or 128 (both /4)
  ps[q][j] = dot_chunk<KH / 4>(Wm + j * K + q * KH, fin + q * KH);
  if (N > 256) {
    if (tid < 2 * (N - 256)) {       // 16 extra tasks: 8 rows x 2 chunks
      int r  = 256 + (tid & 7);
      int qq = tid >> 3;
      ps[qq][r] = dot_chunk<KH / 4>(Wm + r * K + qq * KH, fin + qq * KH);
    }
  }
  __syncthreads();
  if (tid < N) {
    float s = ps[0][tid] + ps[1][tid] + bias[tid];
    fout[tid] = DO_TANH ? tanhf(s) : s;
  }
  __syncthreads();
}

__device__ __forceinline__ void f_eval(const Params& P,
                                       const float* __restrict__ fin,
                                       float* __restrict__ fout,
                                       float* __restrict__ ha,
                                       float* __restrict__ hb,
                                       float (*__restrict__ ps)[DD],
                                       int j, int q, int tid) {
  layer<DD,  WID, true >(P.W0, P.b0, fin, ha,  ps, j, q, tid);
  layer<WID, WID, true >(P.W1, P.b1, ha,  hb,  ps, j, q, tid);
  layer<WID, WID, true >(P.W2, P.b2, hb,  ha,  ps, j, q, tid);
  layer<WID, DD,  false>(P.W3, P.b3, ha,  fout, ps, j, q, tid);
}

__global__ __launch_bounds__(512, 2) void node_integrate(
    const float* __restrict__ ts, const float* __restrict__ xs,
    const float* __restrict__ a_sample, Params P,
    float* __restrict__ out) {
  const int b   = blockIdx.x;
  const int tid = threadIdx.x;
  const int j   = tid & 255;
  const int q   = tid >> 8;

  __shared__ __align__(16) float s_y[DD];
  __shared__ __align__(16) float s_in[DD];
  __shared__ __align__(16) float s_k[DD];
  __shared__ __align__(16) float s_acc[DD];
  __shared__ __align__(16) float s_ha[WID];
  __shared__ __align__(16) float s_hb[WID];
  __shared__ __align__(16) float s_ps[2][DD];

  // y0 = concat(a * exp(-0.1*t0) * sin(pi*x), zeros(AUG))
  if (tid < DD) {
    float v = 0.f;
    if (tid < DATA) {
      float x = xs[(size_t)b * DATA + tid];
      float scale = a_sample[b] * expf(-0.1f * ts[0]);
      v = scale * sinf(3.14159265358979323846f * x);
    }
    s_y[tid] = v;
  }
  __syncthreads();

  if (tid < DATA) out[((size_t)b * NT + 0) * DATA + tid] = s_y[tid];

  for (int t = 0; t < NT - 1; ++t) {
    const float dt = ts[t + 1] - ts[t];
    const float h  = dt * (1.0f / NSUB);
    for (int sub = 0; sub < NSUB; ++sub) {
      // k1
      f_eval(P, s_y, s_k, s_ha, s_hb, s_ps, j, q, tid);
      if (tid < DD) {
        float k1 = s_k[tid];
        s_acc[tid] = (2.0f / 9.0f) * k1;
        s_in[tid]  = s_y[tid] + 0.5f * h * k1;
      }
      __syncthreads();
      // k2
      f_eval(P, s_in, s_k, s_ha, s_hb, s_ps, j, q, tid);
      if (tid < DD) {
        float k2 = s_k[tid];
        s_acc[tid] += (1.0f / 3.0f) * k2;
        s_in[tid] = s_y[tid] + 0.75f * h * k2;
      }
      __syncthreads();
      // k3 + combine
      f_eval(P, s_in, s_k, s_ha, s_hb, s_ps, j, q, tid);
      if (tid < DD) {
        float k3 = s_k[tid];
        s_y[tid] += h * (s_acc[tid] + (4.0f / 9.0f) * k3);
      }
      __syncthreads();
    }
    if (tid < DATA) out[((size_t)b * NT + (t + 1)) * DATA + tid] = s_y[tid];
  }
}

extern "C" void kernel_launch(void* const* d_in, const int* in_sizes, int n_in,
                              void* d_out, int out_size, void* d_ws, size_t ws_size,
                              hipStream_t stream) {
  const float* ts = (const float*)d_in[0];
  const float* xs = (const float*)d_in[1];
  const float* a  = (const float*)d_in[2];
  Params P;
  P.W0 = (const float*)d_in[3];
  P.b0 = (const float*)d_in[4];
  P.W1 = (const float*)d_in[5];
  P.b1 = (const float*)d_in[6];
  P.W2 = (const float*)d_in[7];
  P.b2 = (const float*)d_in[8];
  P.W3 = (const float*)d_in[9];
  P.b3 = (const float*)d_in[10];
  float* out = (float*)d_out;

  hipLaunchKernelGGL(node_integrate, dim3(NB), dim3(512), 0, stream,
                     ts, xs, a, P, out);
}